// Round 1
// baseline (2613.898 us; speedup 1.0000x reference)
//
#include <hip/hip_runtime.h>

#define B_    8
#define N_    8192
#define M_    2000
#define K_    16
#define C1_   128
#define C2_   256
#define OUT_  100
#define SUBP_ 2048   // padded per-batch pitch for subsampled points (KNN2 candidates)

// ---------------------------------------------------------------- helpers
__device__ inline unsigned long long shflxor_u64(unsigned long long v, int m) {
    int lo = __shfl_xor((int)(v & 0xFFFFFFFFull), m, 64);
    int hi = __shfl_xor((int)(v >> 32), m, 64);
    return ((unsigned long long)(unsigned)hi << 32) | (unsigned)lo;
}

// ---------------------------------------------------------------- prep: coords -> float4(x,y,z,|p|^2); pad sub4 sentinels
__global__ __launch_bounds__(256) void prep_kernel(const float* __restrict__ x,
                                                   float4* __restrict__ coords4,
                                                   float4* __restrict__ sub4) {
    int i = blockIdx.x * 256 + threadIdx.x;
    if (i < B_ * N_) {
        float xx = x[i*3+0], yy = x[i*3+1], zz = x[i*3+2];
        float ss = fmaf(zz, zz, fmaf(yy, yy, xx*xx));   // ((x^2+y^2)+z^2)
        coords4[i] = make_float4(xx, yy, zz, ss);
    }
    if (i < B_ * (SUBP_ - M_)) {   // sentinel pads: huge distance, never selected
        int b = i / (SUBP_ - M_), j = i % (SUBP_ - M_);
        sub4[b*SUBP_ + M_ + j] = make_float4(1e15f, 1e15f, 1e15f, 3e30f);
    }
}

// ---------------------------------------------------------------- FPS: 1 block per batch, serial over 1999 picks
#define FPS_T 512
#define FPS_P 16   // points per thread: 512*16 = 8192

__global__ __launch_bounds__(FPS_T) void fps_kernel(const float4* __restrict__ coords4,
                                                    int* __restrict__ fps_idx,
                                                    float4* __restrict__ sub4) {
    int b = blockIdx.x;
    int t = threadIdx.x;
    const float4* C = coords4 + b * N_;
    // 3-slot rotating reduce cell: 1 barrier per iteration (slots i, i+1, i+2 mod 3
    // are read / atomically-written / reset in disjoint barrier intervals)
    __shared__ unsigned long long slot[3];
    if (t < 3) slot[t] = 0ull;

    float px_[FPS_P], py_[FPS_P], pz_[FPS_P], mind[FPS_P];
#pragma unroll
    for (int j = 0; j < FPS_P; ++j) {
        float4 p = C[t + j*FPS_T];
        px_[j] = p.x; py_[j] = p.y; pz_[j] = p.z; mind[j] = 1e30f;
    }
    if (t == 0) { fps_idx[b*M_] = 0; sub4[b*SUBP_] = C[0]; }
    int last = 0;
    __syncthreads();

    for (int i = 1; i < M_; ++i) {
        float4 P = C[last];                 // uniform address -> broadcast load
        unsigned long long best = 0ull;
#pragma unroll
        for (int j = 0; j < FPS_P; ++j) {
            float dx = px_[j] - P.x, dy = py_[j] - P.y, dz = pz_[j] - P.z;
            float d = fmaf(dz, dz, fmaf(dy, dy, dx*dx));   // direct form matches reference FPS
            float m = fminf(mind[j], d);
            mind[j] = m;
            // key: value bits (non-negative floats: bit order == value order), tie -> smaller index
            unsigned long long key = ((unsigned long long)__float_as_uint(m) << 32)
                                   | (unsigned long long)(0xFFFFFFFFu - (unsigned)(t + j*FPS_T));
            if (key > best) best = key;
        }
#pragma unroll
        for (int s = 1; s < 64; s <<= 1) {
            unsigned long long o = shflxor_u64(best, s);
            if (o > best) best = o;
        }
        if ((t & 63) == 0) atomicMax(&slot[i % 3], best);
        __syncthreads();
        unsigned long long kk = slot[i % 3];
        last = (int)(0xFFFFFFFFu - (unsigned)(kk & 0xFFFFFFFFull));
        if (t == 0) {
            slot[(i + 2) % 3] = 0ull;       // prep slot for iteration i+2 (race-free per 3-slot rotation)
            fps_idx[b*M_ + i] = last;
            sub4[b*SUBP_ + i] = C[last];    // gather (w = |p|^2, identical arithmetic to prep)
        }
    }
}

// ---------------------------------------------------------------- KNN: 1 wave per query, exact top-16 (set semantics)
// Pass 1: branchless lane-local sorted-16 of values only (15 CE bubble per candidate).
// Merge:  k-way merge of 64 sorted heads -> T = exact 16th smallest distance.
// Pass 2: ballot-collect indices with d<T, then earliest-index ties d==T (matches lax.top_k stability).
template<int NCH, int PITCH>
__global__ __launch_bounds__(256) void knn_kernel(const float4* __restrict__ cand,
                                                  const float4* __restrict__ qarr,
                                                  int* __restrict__ outIdx) {
    int lane = threadIdx.x & 63;
    int q = blockIdx.x * 4 + (threadIdx.x >> 6);
    int b = q / M_, m = q % M_;
    const float4* Cb = cand + b * PITCH;
    float4 Q = qarr[b * SUBP_ + m];

    float v[16];
#pragma unroll
    for (int tt = 0; tt < 16; ++tt) v[tt] = 3.4e38f;

#pragma unroll 2
    for (int j = 0; j < NCH; ++j) {
        float4 c = Cb[j*64 + lane];
        float dot = fmaf(c.z, Q.z, fmaf(c.y, Q.y, c.x * Q.x));
        float d = fmaf(-2.0f, dot, Q.w + c.w);   // == (qq+ss) - 2*dot, single rounding
        v[15] = fminf(v[15], d);
#pragma unroll
        for (int tt = 15; tt >= 1; --tt) {       // restore sortedness: bubble toward 0
            float lo = fminf(v[tt-1], v[tt]);
            float hi = fmaxf(v[tt-1], v[tt]);
            v[tt-1] = lo; v[tt] = hi;
        }
    }

    float T = 0.0f;
    for (int r = 0; r < 16; ++r) {               // extract global min 16 times (one entry per round)
        float g = v[0];
#pragma unroll
        for (int s = 1; s < 64; s <<= 1) g = fminf(g, __shfl_xor(g, s, 64));
        unsigned long long mk = __ballot(v[0] == g);
        int fl = __ffsll(mk) - 1;                // exactly one lane consumes (value ties resolved)
        if (lane == fl) {
#pragma unroll
            for (int tt = 0; tt < 15; ++tt) v[tt] = v[tt+1];
            v[15] = 3.4e38f;
        }
        T = g;
    }

    unsigned long long mlt = (1ull << lane) - 1ull;
    int base = q * K_;
    int cnt = 0;
    for (int j = 0; j < NCH; ++j) {              // all strictly-closer candidates (<= 15 of them)
        float4 c = Cb[j*64 + lane];
        float dot = fmaf(c.z, Q.z, fmaf(c.y, Q.y, c.x * Q.x));
        float d = fmaf(-2.0f, dot, Q.w + c.w);
        bool lt = d < T;
        unsigned long long m1 = __ballot(lt);
        if (lt) outIdx[base + cnt + __popcll(m1 & mlt)] = j*64 + lane;
        cnt += __popcll(m1);
    }
    int rem = K_ - cnt;                          // >= 1 (T itself); fill with earliest-index ties
    for (int j = 0; j < NCH && rem > 0; ++j) {
        float4 c = Cb[j*64 + lane];
        float dot = fmaf(c.z, Q.z, fmaf(c.y, Q.y, c.x * Q.x));
        float d = fmaf(-2.0f, dot, Q.w + c.w);
        bool eq = (d == T);
        unsigned long long m2 = __ballot(eq);
        int bef = __popcll(m2 & mlt);
        if (eq && bef < rem) outIdx[base + cnt + bef] = j*64 + lane;
        int take = __popcll(m2); if (take > rem) take = rem;
        cnt += take; rem -= take;
    }
}

// ---------------------------------------------------------------- layer 1: feats=[rel(3), ngh(3)] x W1[6,128], relu, max over k
__global__ __launch_bounds__(128) void layer1_kernel(const float4* __restrict__ coords4,
        const float4* __restrict__ sub4, const int* __restrict__ idx1,
        const float* __restrict__ W1, const float* __restrict__ b1,
        float* __restrict__ f1) {
    int q = blockIdx.x;
    int b = q / M_, m = q % M_;
    int c = threadIdx.x;
    __shared__ float4 ngh[K_];
    if (c < K_) ngh[c] = coords4[b*N_ + idx1[q*K_ + c]];
    __syncthreads();
    float4 Q = sub4[b*SUBP_ + m];
    float w0 = W1[c],        w1 = W1[C1_ + c],   w2 = W1[2*C1_ + c];
    float w3 = W1[3*C1_ + c], w4 = W1[4*C1_ + c], w5 = W1[5*C1_ + c];
    float bias = b1[c];
    float mx = -3.4e38f;
#pragma unroll
    for (int k = 0; k < K_; ++k) {
        float4 n = ngh[k];
        float rx = n.x - Q.x, ry = n.y - Q.y, rz = n.z - Q.z;
        float s = rx*w0; s = fmaf(ry,w1,s); s = fmaf(rz,w2,s);
        s = fmaf(n.x,w3,s); s = fmaf(n.y,w4,s); s = fmaf(n.z,w5,s);
        s += bias;
        s = fmaxf(s, 0.0f);
        mx = fmaxf(mx, s);
    }
    f1[q*C1_ + c] = mx;
}

// ---------------------------------------------------------------- layer 2: feats=[rel(3), fg(128)] x W2[131,256], relu, max over k
#define FPAD 20   // row pitch (floats): 16B-aligned rows, odd-ish banking for staging
__global__ __launch_bounds__(64) void layer2_kernel(const float4* __restrict__ sub4,
        const float* __restrict__ f1, const int* __restrict__ idx2,
        const float* __restrict__ W2, const float* __restrict__ b2,
        float* __restrict__ f2) {
    int q = blockIdx.x;
    int b = q / M_, m = q % M_;
    int t = threadIdx.x;
    __shared__ __align__(16) float feat[(3 + C1_) * FPAD];  // feat[f][k], k=0..15
    __shared__ int nidx[K_];
    float4 Q = sub4[b*SUBP_ + m];
    if (t < K_) {
        int ik = idx2[q*K_ + t];
        nidx[t] = ik;
        float4 n = sub4[b*SUBP_ + ik];
        feat[0*FPAD + t] = n.x - Q.x;
        feat[1*FPAD + t] = n.y - Q.y;
        feat[2*FPAD + t] = n.z - Q.z;
    }
    __syncthreads();
    for (int e = t; e < K_ * C1_; e += 64) {    // stage gathered f1 rows: feat[3+cc][k]
        int k = e >> 7, cc = e & 127;
        feat[(3 + cc)*FPAD + k] = f1[(b*M_ + nidx[k])*C1_ + cc];
    }
    __syncthreads();

    float acc[K_][4];
#pragma unroll
    for (int k = 0; k < K_; ++k) { acc[k][0]=0.f; acc[k][1]=0.f; acc[k][2]=0.f; acc[k][3]=0.f; }
    int c0 = t * 4;                              // 4 channels per thread, 64 threads = 256 ch
    for (int f = 0; f < 3 + C1_; ++f) {
        float4 w  = *(const float4*)(W2 + f*C2_ + c0);
        const float* row = feat + f*FPAD;
        float4 g0 = *(const float4*)(row + 0);
        float4 g1 = *(const float4*)(row + 4);
        float4 g2 = *(const float4*)(row + 8);
        float4 g3 = *(const float4*)(row + 12);
        float gk[16] = {g0.x,g0.y,g0.z,g0.w, g1.x,g1.y,g1.z,g1.w,
                        g2.x,g2.y,g2.z,g2.w, g3.x,g3.y,g3.z,g3.w};
#pragma unroll
        for (int k = 0; k < K_; ++k) {
            acc[k][0] = fmaf(gk[k], w.x, acc[k][0]);
            acc[k][1] = fmaf(gk[k], w.y, acc[k][1]);
            acc[k][2] = fmaf(gk[k], w.z, acc[k][2]);
            acc[k][3] = fmaf(gk[k], w.w, acc[k][3]);
        }
    }
    float4 bb = *(const float4*)(b2 + c0);
    float mx0 = -3.4e38f, mx1 = -3.4e38f, mx2 = -3.4e38f, mx3 = -3.4e38f;
#pragma unroll
    for (int k = 0; k < K_; ++k) {
        float h0 = fmaxf(acc[k][0] + bb.x, 0.0f);
        float h1 = fmaxf(acc[k][1] + bb.y, 0.0f);
        float h2 = fmaxf(acc[k][2] + bb.z, 0.0f);
        float h3 = fmaxf(acc[k][3] + bb.w, 0.0f);
        mx0 = fmaxf(mx0, h0); mx1 = fmaxf(mx1, h1);
        mx2 = fmaxf(mx2, h2); mx3 = fmaxf(mx3, h3);
    }
    *(float4*)(f2 + q*C2_ + c0) = make_float4(mx0, mx1, mx2, mx3);
}

// ---------------------------------------------------------------- fused adaptive max+avg pool
__global__ __launch_bounds__(256) void pool_kernel(const float* __restrict__ f2,
                                                   float* __restrict__ out) {
    int bo = blockIdx.x;
    int b = bo / OUT_, o = bo % OUT_;
    int c = threadIdx.x;
    float mx = -3.4e38f, sm = 0.0f;
#pragma unroll
    for (int w = 0; w < M_/OUT_; ++w) {
        float v = f2[(b*M_ + o*(M_/OUT_) + w)*C2_ + c];
        mx = fmaxf(mx, v);
        sm += v;
    }
    out[(b*C2_ + c)*OUT_ + o] = mx + sm / (float)(M_/OUT_);
}

// ---------------------------------------------------------------- launch
extern "C" void kernel_launch(void* const* d_in, const int* in_sizes, int n_in,
                              void* d_out, int out_size, void* d_ws, size_t ws_size,
                              hipStream_t stream) {
    const float* x  = (const float*)d_in[0];
    const float* W1 = (const float*)d_in[1];
    const float* b1 = (const float*)d_in[2];
    const float* W2 = (const float*)d_in[3];
    const float* b2 = (const float*)d_in[4];
    float* out = (float*)d_out;

    char* ws = (char*)d_ws;
    size_t off = 0;
    auto alloc = [&](size_t bytes) {
        void* p = ws + off;
        off += (bytes + 255) & ~(size_t)255;
        return p;
    };
    float4* coords4 = (float4*)alloc((size_t)B_*N_*sizeof(float4));     // 2 MB
    float4* sub4    = (float4*)alloc((size_t)B_*SUBP_*sizeof(float4));  // 256 KB
    int*    fpsIdx  = (int*)  alloc((size_t)B_*M_*sizeof(int));
    int*    idx1    = (int*)  alloc((size_t)B_*M_*K_*sizeof(int));      // 2 MB
    int*    idx2    = (int*)  alloc((size_t)B_*M_*K_*sizeof(int));      // 2 MB
    float*  f1      = (float*)alloc((size_t)B_*M_*C1_*sizeof(float));   // 8 MB
    float*  f2      = (float*)alloc((size_t)B_*M_*C2_*sizeof(float));   // 16 MB

    prep_kernel<<<(B_*N_ + 255)/256, 256, 0, stream>>>(x, coords4, sub4);
    fps_kernel<<<B_, FPS_T, 0, stream>>>(coords4, fpsIdx, sub4);
    knn_kernel<N_/64,    N_   ><<<B_*M_/4, 256, 0, stream>>>(coords4, sub4, idx1);
    knn_kernel<SUBP_/64, SUBP_><<<B_*M_/4, 256, 0, stream>>>(sub4,    sub4, idx2);
    layer1_kernel<<<B_*M_, 128, 0, stream>>>(coords4, sub4, idx1, W1, b1, f1);
    layer2_kernel<<<B_*M_,  64, 0, stream>>>(sub4, f1, idx2, W2, b2, f2);
    pool_kernel<<<B_*OUT_, 256, 0, stream>>>(f2, out);
}